// Round 1
// baseline (462.829 us; speedup 1.0000x reference)
//
#include <hip/hip_runtime.h>

typedef __bf16 bf16x8 __attribute__((ext_vector_type(8)));
typedef float f32x4 __attribute__((ext_vector_type(4)));

// LDS layout (bytes). H overlaps A+W1T (both dead when H is written).
#define OFF_A     0        // bf16 [128][72]
#define OFF_W1T   18432    // bf16 [128][72]
#define OFF_H     0        // bf16 [128][136]  (overlaps A+W1T)
#define OFF_XS    36864    // bf16 [16][3][132]
#define OFF_W2T   49536    // bf16 [16][136]
#define OFF_RM    53888    // float[128]
#define OFF_B1    54400    // float[128]
#define OFF_B2    54912    // float[16]
#define SMEM_BYTES 54976

__global__ __launch_bounds__(256, 2) void nca_main(
    const float* __restrict__ x, const float* __restrict__ rm,
    const float* __restrict__ W1, const float* __restrict__ b1,
    const float* __restrict__ W2, const float* __restrict__ b2,
    float* __restrict__ out, float* __restrict__ anew, unsigned char* __restrict__ pre)
{
    __shared__ __align__(16) char smem[SMEM_BYTES];
    __bf16* A   = (__bf16*)(smem + OFF_A);
    __bf16* W1T = (__bf16*)(smem + OFF_W1T);
    __bf16* H   = (__bf16*)(smem + OFF_H);
    __bf16* XS  = (__bf16*)(smem + OFF_XS);
    __bf16* W2T = (__bf16*)(smem + OFF_W2T);
    float*  RM  = (float*)(smem + OFF_RM);
    float*  B1  = (float*)(smem + OFF_B1);
    float*  B2  = (float*)(smem + OFF_B2);

    const int tid = threadIdx.x;
    // chunked XCD swizzle: 16384 blocks, 8 XCDs -> each XCD gets contiguous 2048
    int raw = blockIdx.x;
    int wg  = (raw & 7) * 2048 + (raw >> 3);
    int b   = wg >> 9;          // 512 strips per image (256 rows x 2 halves)
    int rem = wg & 511;
    int h   = rem >> 1;
    int w0  = (rem & 1) << 7;

    // ---- stage weights (bf16, B-transposed so K is contiguous) ----
    for (int idx = tid; idx < 64 * 128; idx += 256) {
        int n = idx & 127, k = idx >> 7;
        float v = (k < 48) ? W1[k * 128 + n] : 0.f;
        W1T[n * 72 + k] = (__bf16)v;
    }
    for (int idx = tid; idx < 128 * 16; idx += 256) {
        int c = idx & 15, k = idx >> 4;
        W2T[c * 136 + k] = (__bf16)W2[k * 16 + c];
    }
    if (tid < 128) { B1[tid] = b1[tid]; RM[tid] = rm[(b * 256 + h) * 256 + w0 + tid]; }
    else if (tid < 144) { B2[tid - 128] = b2[tid - 128]; }

    // ---- stage x rows h-1..h+1, cols w0-1..w0+128 -> XS[ch][r][c] (bf16) ----
    for (int idx = tid; idx < 3 * 130 * 4; idx += 256) {
        int r   = idx / 520;
        int rr  = idx - r * 520;
        int c   = rr >> 2;
        int chq = rr & 3;
        int gh = h - 1 + r, gw = w0 - 1 + c;
        float4 v = make_float4(0.f, 0.f, 0.f, 0.f);
        if (gh >= 0 && gh < 256 && gw >= 0 && gw < 256)
            v = *reinterpret_cast<const float4*>(x + (((size_t)(b * 256 + gh) * 256 + gw) * 16 + chq * 4));
        __bf16* d = XS + (chq * 4) * 396 + r * 132 + c;
        d[0]       = (__bf16)v.x;
        d[396]     = (__bf16)v.y;
        d[2 * 396] = (__bf16)v.z;
        d[3 * 396] = (__bf16)v.w;
    }
    __syncthreads();

    // ---- perceive conv -> A[p][3ch+j], K-pad zeros, pre-alive mask ----
    {
        int p = tid & 127, half = tid >> 7;
        int ch0 = half * 8;
        #pragma unroll
        for (int ch = ch0; ch < ch0 + 8; ++ch) {
            const __bf16* base = XS + ch * 396 + p;
            float v00 = (float)base[0],   v01 = (float)base[1],   v02 = (float)base[2];
            float v10 = (float)base[132], v12 = (float)base[134];
            float v21 = (float)base[265];
            float y0 = 0.125f * (-v00 - 2.f * v01 - v02 - v10 + v12);
            float y1 = 0.25f * (v12 - v10) + v21;
            float y2 = 0.125f * (v00 + 2.f * v01 + v02 - v10 + v12);
            __bf16* ap = A + p * 72 + 3 * ch;
            ap[0] = (__bf16)y0; ap[1] = (__bf16)y1; ap[2] = (__bf16)y2;
        }
        __bf16* zp = A + p * 72 + 48 + half * 8;
        #pragma unroll
        for (int u = 0; u < 8; ++u) zp[u] = (__bf16)0.f;
        if (half == 0) {
            const __bf16* ab = XS + 3 * 396 + p;  // alpha channel
            float m = -1e30f;
            #pragma unroll
            for (int dh = 0; dh < 3; ++dh)
                #pragma unroll
                for (int dw = 0; dw < 3; ++dw)
                    m = fmaxf(m, (float)ab[dh * 132 + dw]);
            pre[(b * 256 + h) * 256 + w0 + p] = (m > 0.1f) ? 1 : 0;
        }
    }
    __syncthreads();

    // ---- GEMM1: A[128x64] @ W1[64x128] -> acc (fp32) ----
    const int l = tid & 63;
    const int wv = tid >> 6;
    const int lrow = l & 15, kg = l >> 4;

    f32x4 acc[2][8];
    #pragma unroll
    for (int i = 0; i < 2; ++i)
        #pragma unroll
        for (int j = 0; j < 8; ++j)
            acc[i][j] = f32x4{0.f, 0.f, 0.f, 0.f};

    bf16x8 af[2][2], bfr[8][2];
    #pragma unroll
    for (int ti = 0; ti < 2; ++ti)
        #pragma unroll
        for (int kk = 0; kk < 2; ++kk)
            af[ti][kk] = *(const bf16x8*)(A + ((wv * 2 + ti) * 16 + lrow) * 72 + kk * 32 + kg * 8);
    #pragma unroll
    for (int nt = 0; nt < 8; ++nt)
        #pragma unroll
        for (int kk = 0; kk < 2; ++kk)
            bfr[nt][kk] = *(const bf16x8*)(W1T + (nt * 16 + lrow) * 72 + kk * 32 + kg * 8);

    #pragma unroll
    for (int kk = 0; kk < 2; ++kk)
        #pragma unroll
        for (int ti = 0; ti < 2; ++ti)
            #pragma unroll
            for (int nt = 0; nt < 8; ++nt)
                acc[ti][nt] = __builtin_amdgcn_mfma_f32_16x16x32_bf16(af[ti][kk], bfr[nt][kk], acc[ti][nt], 0, 0, 0);

    __syncthreads();  // everyone done reading A/W1T before H overwrites them

    // ---- bias + relu -> H bf16 [128][136] ----
    #pragma unroll
    for (int ti = 0; ti < 2; ++ti)
        #pragma unroll
        for (int nt = 0; nt < 8; ++nt) {
            int col = nt * 16 + lrow;
            float bias = B1[col];
            #pragma unroll
            for (int r = 0; r < 4; ++r) {
                float hv = fmaxf(acc[ti][nt][r] + bias, 0.f);
                H[((wv * 2 + ti) * 16 + kg * 4 + r) * 136 + col] = (__bf16)hv;
            }
        }
    __syncthreads();

    // ---- GEMM2: H[128x128] @ W2[128x16] ----
    f32x4 acc2[2];
    acc2[0] = f32x4{0.f, 0.f, 0.f, 0.f};
    acc2[1] = f32x4{0.f, 0.f, 0.f, 0.f};
    bf16x8 bh[4];
    #pragma unroll
    for (int kk = 0; kk < 4; ++kk)
        bh[kk] = *(const bf16x8*)(W2T + lrow * 136 + kk * 32 + kg * 8);
    #pragma unroll
    for (int ti = 0; ti < 2; ++ti)
        #pragma unroll
        for (int kk = 0; kk < 4; ++kk) {
            bf16x8 ah = *(const bf16x8*)(H + ((wv * 2 + ti) * 16 + lrow) * 136 + kk * 32 + kg * 8);
            acc2[ti] = __builtin_amdgcn_mfma_f32_16x16x32_bf16(ah, bh[kk], acc2[ti], 0, 0, 0);
        }

    // ---- epilogue: dx + stochastic update, write x_new, alpha_new ----
    {
        int c = lrow;
        float bias2 = B2[c];
        size_t pixbase = (size_t)(b * 256 + h) * 256 + w0;
        #pragma unroll
        for (int ti = 0; ti < 2; ++ti)
            #pragma unroll
            for (int r = 0; r < 4; ++r) {
                int p = (wv * 2 + ti) * 16 + kg * 4 + r;
                float dx = acc2[ti][r] + bias2;
                float u = (RM[p] < 0.5f) ? 1.f : 0.f;
                float xv = x[(pixbase + p) * 16 + c];
                float xn = xv + dx * u;
                out[(pixbase + p) * 16 + c] = xn;
                if (c == 3) anew[pixbase + p] = xn;
            }
    }
}

// pass 2: life mask -> zero dead pixels (expected ~none with this data)
__global__ __launch_bounds__(256) void nca_life(
    const float* __restrict__ anew, const unsigned char* __restrict__ pre,
    float* __restrict__ out)
{
    int q = blockIdx.x * 256 + threadIdx.x;
    int w = q & 255, hh = (q >> 8) & 255;
    float m = -1e30f;
    #pragma unroll
    for (int dh = -1; dh <= 1; ++dh) {
        int h2 = hh + dh;
        if (h2 < 0 || h2 > 255) continue;
        #pragma unroll
        for (int dw = -1; dw <= 1; ++dw) {
            int w2 = w + dw;
            if (w2 < 0 || w2 > 255) continue;
            m = fmaxf(m, anew[q + dh * 256 + dw]);
        }
    }
    if (!((pre[q] != 0) && (m > 0.1f))) {
        float4 z = make_float4(0.f, 0.f, 0.f, 0.f);
        float4* o = (float4*)(out + (size_t)q * 16);
        o[0] = z; o[1] = z; o[2] = z; o[3] = z;
    }
}

extern "C" void kernel_launch(void* const* d_in, const int* in_sizes, int n_in,
                              void* d_out, int out_size, void* d_ws, size_t ws_size,
                              hipStream_t stream) {
    (void)in_sizes; (void)n_in; (void)out_size; (void)ws_size;
    const float* x  = (const float*)d_in[0];
    const float* rm = (const float*)d_in[1];
    const float* W1 = (const float*)d_in[2];
    const float* b1 = (const float*)d_in[3];
    const float* W2 = (const float*)d_in[4];
    const float* b2 = (const float*)d_in[5];
    float* out = (float*)d_out;
    // workspace: alpha_new (2M floats = 8 MB) + pre mask (2M bytes)
    float* anew = (float*)d_ws;
    unsigned char* pre = (unsigned char*)d_ws + (size_t)2097152 * 4;

    nca_main<<<dim3(16384), dim3(256), 0, stream>>>(x, rm, W1, b1, W2, b2, out, anew, pre);
    nca_life<<<dim3(8192), dim3(256), 0, stream>>>(anew, pre, out);
}

// Round 2
// 139.325 us; speedup vs baseline: 3.3220x; 3.3220x over previous
//
#include <hip/hip_runtime.h>

typedef __bf16 bf16x8 __attribute__((ext_vector_type(8)));
typedef float f32x4 __attribute__((ext_vector_type(4)));

#define XS_COLS 132
#define XS_CHP 24                              // channel pitch (pad 16->24): conflict-free b128
#define XS_SLOT_B (XS_COLS * XS_CHP * 2)       // 6336 B per row-slot
#define H_BYTES 32768                          // H[128 px][128 k] bf16, XOR-swizzled
#define OFF_XS H_BYTES
#define SMEM_BYTES (H_BYTES + 4 * XS_SLOT_B)   // 58112 B

__device__ __forceinline__ unsigned short bfbits(float f) {
    __bf16 b = (__bf16)f;
    return __builtin_bit_cast(unsigned short, b);
}

__global__ __launch_bounds__(512, 4) void nca_main(
    const float* __restrict__ x, const float* __restrict__ rm,
    const float* __restrict__ W1, const float* __restrict__ b1,
    const float* __restrict__ W2, const float* __restrict__ b2,
    float* __restrict__ out, float* __restrict__ anew, unsigned char* __restrict__ pre)
{
    __shared__ __align__(16) char smem[SMEM_BYTES];
    char* Hb  = smem;
    char* XSb = smem + OFF_XS;

    const int tid  = threadIdx.x;
    const int lane = tid & 63;
    const int wid  = tid >> 6;      // 0..7
    const int lrow = lane & 15;
    const int kg   = lane >> 4;     // 0..3
    const int kgh  = kg >> 1;       // 0..1
    const int kgl  = kg & 1;

    // block -> (img, col-half, row-group of 8)
    int raw = blockIdx.x;
    int wg  = (raw & 7) * 256 + (raw >> 3);   // XCD-chunked swizzle (2048 = 8*256)
    int img = wg >> 6;
    int rem = wg & 63;
    int w0  = (rem >> 5) << 7;
    int h0  = (rem & 31) * 8;

    const size_t imgbase = (size_t)img * 65536;

    // G1 wave split: r = n-range quarter (2 Mtiles), cq = px 64-half
    const int r  = wid >> 1;
    const int cq = wid & 1;

    // ---- init: Wt fragments (conv folded into W1; 6 nonzero taps, K=96) ----
    // taps tp: 0:(-1,-1) 1:(-1,0) 2:(-1,+1) 3:(0,-1) 4:(0,+1) 5:(+1,0)
    bf16x8 wt[2][3];
    #pragma unroll
    for (int m = 0; m < 2; ++m) {
        int n = (r * 2 + m) * 16 + lrow;
        #pragma unroll
        for (int kk = 0; kk < 3; ++kk) {
            float c0, c1, c2;
            if (kk == 0) {        // tp0 / tp1
                c0 = kgh ? -0.25f : -0.125f; c1 = 0.f; c2 = kgh ? 0.25f : 0.125f;
            } else if (kk == 1) { // tp2 / tp3
                c0 = kgh ? -0.125f : -0.125f;
                c1 = kgh ? -0.25f  : 0.f;
                c2 = kgh ? -0.125f : 0.125f;
            } else {              // tp4 / tp5
                c0 = kgh ? 0.f : 0.125f; c1 = kgh ? 1.f : 0.25f; c2 = kgh ? 0.f : 0.125f;
            }
            bf16x8 v;
            #pragma unroll
            for (int j = 0; j < 8; ++j) {
                int ch = kgl * 8 + j;
                float wv = c0 * W1[(3 * ch + 0) * 128 + n]
                         + c1 * W1[(3 * ch + 1) * 128 + n]
                         + c2 * W1[(3 * ch + 2) * 128 + n];
                v[j] = (__bf16)wv;
            }
            wt[m][kk] = v;
        }
    }

    // W2 fragments (A-operand of transposed GEMM2: rows = out-channel c = lrow)
    bf16x8 w2f[4];
    #pragma unroll
    for (int kk = 0; kk < 4; ++kk) {
        bf16x8 v;
        #pragma unroll
        for (int j = 0; j < 8; ++j) {
            int k = kk * 32 + kg * 8 + j;
            v[j] = (__bf16)W2[k * 16 + lrow];
        }
        w2f[kk] = v;
    }

    f32x4 b1q[2];
    #pragma unroll
    for (int m = 0; m < 2; ++m)
        b1q[m] = *reinterpret_cast<const f32x4*>(b1 + (r * 2 + m) * 16 + kg * 4);
    const f32x4 b2q = *reinterpret_cast<const f32x4*>(b2 + kg * 4);

    // ---- prologue: stage rows h0-1 .. h0+1 into XS ring (slot = row mod 4) ----
    #pragma unroll
    for (int rr = 0; rr < 3; ++rr) {
        int gh = h0 - 1 + rr;
        int slot = (gh + 4) & 3;
        for (int idx = tid; idx < 520; idx += 512) {
            int col = idx >> 2, chq = idx & 3;
            int gw = w0 + col - 1;
            float4 v = make_float4(0.f, 0.f, 0.f, 0.f);
            if (gh >= 0 && gh < 256 && gw >= 0 && gw < 256)
                v = *reinterpret_cast<const float4*>(x + (imgbase + (size_t)gh * 256 + gw) * 16 + chq * 4);
            ushort4 q = { bfbits(v.x), bfbits(v.y), bfbits(v.z), bfbits(v.w) };
            *reinterpret_cast<ushort4*>(XSb + slot * XS_SLOT_B + col * 48 + chq * 8) = q;
        }
    }
    __syncthreads();

    for (int i = 0; i < 8; ++i) {
        int h = h0 + i;
        int sbm = ((h + 3) & 3) * XS_SLOT_B;   // row h-1
        int sb0 = ((h + 4) & 3) * XS_SLOT_B;   // row h
        int sbp = ((h + 5) & 3) * XS_SLOT_B;   // row h+1

        // ---- GEMM1 (transposed): C1T[n][px] ; B-frags = raw shifted x from XS ----
        #pragma unroll
        for (int t = 0; t < 4; ++t) {
            int pxl = cq * 64 + t * 16 + lrow;
            int colbase = (pxl + 1) * 48 + kgl * 16;
            const char* a0p = XSb + sbm + colbase + (kgh ? 0 : -48);                       // (-1,-1)/(-1,0)
            const char* a1p = kgh ? (XSb + sb0 + colbase - 48) : (XSb + sbm + colbase + 48); // (0,-1)/(-1,+1)
            const char* a2p = kgh ? (XSb + sbp + colbase)      : (XSb + sb0 + colbase + 48); // (+1,0)/(0,+1)
            bf16x8 bf0 = *reinterpret_cast<const bf16x8*>(a0p);
            bf16x8 bf1 = *reinterpret_cast<const bf16x8*>(a1p);
            bf16x8 bf2 = *reinterpret_cast<const bf16x8*>(a2p);
            f32x4 a0 = {0.f, 0.f, 0.f, 0.f}, a1 = {0.f, 0.f, 0.f, 0.f};
            a0 = __builtin_amdgcn_mfma_f32_16x16x32_bf16(wt[0][0], bf0, a0, 0, 0, 0);
            a1 = __builtin_amdgcn_mfma_f32_16x16x32_bf16(wt[1][0], bf0, a1, 0, 0, 0);
            a0 = __builtin_amdgcn_mfma_f32_16x16x32_bf16(wt[0][1], bf1, a0, 0, 0, 0);
            a1 = __builtin_amdgcn_mfma_f32_16x16x32_bf16(wt[1][1], bf1, a1, 0, 0, 0);
            a0 = __builtin_amdgcn_mfma_f32_16x16x32_bf16(wt[0][2], bf2, a0, 0, 0, 0);
            a1 = __builtin_amdgcn_mfma_f32_16x16x32_bf16(wt[1][2], bf2, a1, 0, 0, 0);
            #pragma unroll
            for (int m = 0; m < 2; ++m) {
                f32x4 hv = m ? a1 : a0;
                f32x4 bq = b1q[m];
                ushort4 q;
                q.x = bfbits(fmaxf(hv[0] + bq[0], 0.f));
                q.y = bfbits(fmaxf(hv[1] + bq[1], 0.f));
                q.z = bfbits(fmaxf(hv[2] + bq[2], 0.f));
                q.w = bfbits(fmaxf(hv[3] + bq[3], 0.f));
                int n0 = (r * 2 + m) * 16 + kg * 4;
                int chunk = (n0 >> 3) ^ (pxl & 7);
                *reinterpret_cast<ushort4*>(Hb + pxl * 256 + chunk * 16 + ((n0 >> 2) & 1) * 8) = q;
            }
        }
        __syncthreads();

        // ---- part 2: stage(h+2) loads issued early; GEMM2T; epilogue; stage writes ----
        float4 sv0 = make_float4(0.f, 0.f, 0.f, 0.f), sv1 = make_float4(0.f, 0.f, 0.f, 0.f);
        const bool do_stage = (i < 7);
        const int gh2 = h + 2;
        if (do_stage) {
            int col0 = tid >> 2, chq0 = tid & 3;
            int gw = w0 + col0 - 1;
            if (gh2 < 256 && gw >= 0 && gw < 256)
                sv0 = *reinterpret_cast<const float4*>(x + (imgbase + (size_t)gh2 * 256 + gw) * 16 + chq0 * 4);
            if (tid < 8) {
                int col1 = 128 + (tid >> 2), gw1 = w0 + col1 - 1;
                if (gh2 < 256 && gw1 >= 0 && gw1 < 256)
                    sv1 = *reinterpret_cast<const float4*>(x + (imgbase + (size_t)gh2 * 256 + gw1) * 16 + (tid & 3) * 4);
            }
        }

        // GEMM2 (transposed): dxT[c][px], wave owns 16 px
        const int pxl2 = wid * 16 + lrow;
        f32x4 acc2 = {0.f, 0.f, 0.f, 0.f};
        #pragma unroll
        for (int kk = 0; kk < 4; ++kk) {
            int chunk = (4 * kk + kg) ^ (pxl2 & 7);
            bf16x8 hb = *reinterpret_cast<const bf16x8*>(Hb + pxl2 * 256 + chunk * 16);
            acc2 = __builtin_amdgcn_mfma_f32_16x16x32_bf16(w2f[kk], hb, acc2, 0, 0, 0);
        }

        // epilogue: lane holds dx for 4 consecutive channels kg*4.. of pixel pxl2
        size_t pix = imgbase + (size_t)h * 256 + w0 + pxl2;
        float upd = (rm[pix] < 0.5f) ? 1.f : 0.f;
        float4 xv = *reinterpret_cast<const float4*>(x + pix * 16 + kg * 4);
        float4 xn;
        xn.x = xv.x + (acc2[0] + b2q[0]) * upd;
        xn.y = xv.y + (acc2[1] + b2q[1]) * upd;
        xn.z = xv.z + (acc2[2] + b2q[2]) * upd;
        xn.w = xv.w + (acc2[3] + b2q[3]) * upd;
        *reinterpret_cast<float4*>(out + pix * 16 + kg * 4) = xn;
        if (kg == 0) anew[pix] = xn.w;          // channel 3 = alpha_new
        if (kg == 1) {                          // pre-alive mask from OLD alpha (XS ch 3)
            float mx = -1e30f;
            #pragma unroll
            for (int dwi = 0; dwi < 3; ++dwi) {
                int ca = (pxl2 + dwi) * 48 + 6;
                mx = fmaxf(mx, (float)*reinterpret_cast<const __bf16*>(XSb + sbm + ca));
                mx = fmaxf(mx, (float)*reinterpret_cast<const __bf16*>(XSb + sb0 + ca));
                mx = fmaxf(mx, (float)*reinterpret_cast<const __bf16*>(XSb + sbp + ca));
            }
            pre[pix] = (mx > 0.1f) ? (unsigned char)1 : (unsigned char)0;
        }

        if (do_stage) {
            int slot = (gh2 + 4) & 3;
            {
                int col0 = tid >> 2, chq0 = tid & 3;
                ushort4 q = { bfbits(sv0.x), bfbits(sv0.y), bfbits(sv0.z), bfbits(sv0.w) };
                *reinterpret_cast<ushort4*>(XSb + slot * XS_SLOT_B + col0 * 48 + chq0 * 8) = q;
            }
            if (tid < 8) {
                int col1 = 128 + (tid >> 2);
                ushort4 q = { bfbits(sv1.x), bfbits(sv1.y), bfbits(sv1.z), bfbits(sv1.w) };
                *reinterpret_cast<ushort4*>(XSb + slot * XS_SLOT_B + col1 * 48 + (tid & 3) * 8) = q;
            }
        }
        __syncthreads();
    }
}

// pass 2: life mask -> zero dead pixels (expected ~none with this data)
__global__ __launch_bounds__(256) void nca_life(
    const float* __restrict__ anew, const unsigned char* __restrict__ pre,
    float* __restrict__ out)
{
    int q = blockIdx.x * 256 + threadIdx.x;
    int w = q & 255, hh = (q >> 8) & 255;
    float m = -1e30f;
    #pragma unroll
    for (int dh = -1; dh <= 1; ++dh) {
        int h2 = hh + dh;
        if (h2 < 0 || h2 > 255) continue;
        #pragma unroll
        for (int dw = -1; dw <= 1; ++dw) {
            int w2 = w + dw;
            if (w2 < 0 || w2 > 255) continue;
            m = fmaxf(m, anew[q + dh * 256 + dw]);
        }
    }
    if (!((pre[q] != 0) && (m > 0.1f))) {
        float4 z = make_float4(0.f, 0.f, 0.f, 0.f);
        float4* o = (float4*)(out + (size_t)q * 16);
        o[0] = z; o[1] = z; o[2] = z; o[3] = z;
    }
}

extern "C" void kernel_launch(void* const* d_in, const int* in_sizes, int n_in,
                              void* d_out, int out_size, void* d_ws, size_t ws_size,
                              hipStream_t stream) {
    (void)in_sizes; (void)n_in; (void)out_size; (void)ws_size;
    const float* x  = (const float*)d_in[0];
    const float* rm = (const float*)d_in[1];
    const float* W1 = (const float*)d_in[2];
    const float* b1 = (const float*)d_in[3];
    const float* W2 = (const float*)d_in[4];
    const float* b2 = (const float*)d_in[5];
    float* out = (float*)d_out;
    float* anew = (float*)d_ws;
    unsigned char* pre = (unsigned char*)d_ws + (size_t)2097152 * 4;

    nca_main<<<dim3(2048), dim3(512), 0, stream>>>(x, rm, W1, b1, W2, b2, out, anew, pre);
    nca_life<<<dim3(8192), dim3(256), 0, stream>>>(anew, pre, out);
}